// Round 3
// baseline (502.896 us; speedup 1.0000x reference)
//
#include <hip/hip_runtime.h>
#include <hip/hip_bf16.h>
#include <stdint.h>

// LinearTimeSelfAttention MI355X, round 7:
//  - 3-kernel pipeline (R1's structure, proven -14..18 us vs 4-kernel):
//    memset(tail) -> k1 -> k2bc -> k3. No k2a.
//  - k1 keeps R2's LDS-staged W build (coalesced 256B loads) + contiguous
//    tile runs (proven: k1 dropped >=22 us).
//  - Tail: R1's 2.16M memory-side fp32 RMWs (WRITE_SIZE=8448KB convoy,
//    ~20 us) replaced by "last-arriver" group reduction: blocks stream
//    16.9KB partials, 1 counter atomic each; 64th arriver of each 64-block
//    group sums the group into ctxP[g]. 512 atomics total, no spin.
// Folding: y = Bm@x + cvec; Bm = A@W_q; A = (W_out ctx)/S;
// ctx = sum_n e^k v^T; S = sum_n e^k.

#define NPOS 147456      // 384*384
#define NTILES 2304      // NPOS / 64
#define NB1 512          // 2 blocks/CU exactly

typedef __attribute__((ext_vector_type(8))) short short8;
typedef __attribute__((ext_vector_type(4))) float floatx4;

__device__ __forceinline__ uint16_t f2bf(float f) {
    uint32_t u = __float_as_uint(f);
    return (uint16_t)((u + 0x7fffu + ((u >> 16) & 1u)) >> 16);   // RNE
}
__device__ __forceinline__ uint32_t pack2(float a, float b) {
#if __has_builtin(__builtin_amdgcn_cvt_pk_bf16_f32)
    auto r = __builtin_amdgcn_cvt_pk_bf16_f32(a, b);
    uint32_t u; __builtin_memcpy(&u, &r, sizeof(u));
    return u;
#else
    return (uint32_t)f2bf(a) | ((uint32_t)f2bf(b) << 16);
#endif
}

// strides in 32-bit LDS words
#define XS_STRIDE 68     // 136 bf16 per n-row (128 ch + 8 pad)
#define PS_STRIDE 36     // 72 bf16 per kvrow (64 n + 8 pad)
#define WST_STRIDE 132   // W staging: 128 f32 + 4 pad

// ---- k1 helpers ----
__device__ __forceinline__ void k1_load(const float* __restrict__ xb, float* pf) {
    #pragma unroll
    for (int i = 0; i < 32; ++i) pf[i] = xb[(size_t)i * NPOS];
}
__device__ __forceinline__ void k1_store(uint32_t* Xsbuf, const float* pf, int lane, int c0) {
    #pragma unroll
    for (int i = 0; i < 8; ++i) {
        uint2 w;
        w.x = pack2(pf[i * 4 + 0], pf[i * 4 + 1]);
        w.y = pack2(pf[i * 4 + 2], pf[i * 4 + 3]);
        *(uint2*)&Xsbuf[lane * XS_STRIDE + (c0 + i * 4) / 2] = w;
    }
}
__device__ __forceinline__ void k1_tile(
    const uint32_t* __restrict__ Xsbuf, uint32_t* __restrict__ Psw,
    const short8 (&wfr)[4][4], const float (&biasv)[4],
    floatx4 (&acc2)[4], float (&sacc)[2], int m, int quad)
{
    // phase A: P^T[n][local kvrow] = X^T W^T + b   (local rows: 0-31 k, 32-63 v)
    #pragma unroll
    for (int nt = 0; nt < 4; ++nt) {
        short8 afr[4];
        #pragma unroll
        for (int ks = 0; ks < 4; ++ks)
            afr[ks] = *(const short8*)&Xsbuf[(nt * 16 + m) * XS_STRIDE + ks * 16 + quad * 4];
        floatx4 pa[4];
        #pragma unroll
        for (int kt = 0; kt < 4; ++kt) pa[kt] = (floatx4){0.f, 0.f, 0.f, 0.f};
        #pragma unroll
        for (int ks = 0; ks < 4; ++ks)
            #pragma unroll
            for (int kt = 0; kt < 4; ++kt)
                pa[kt] = __builtin_amdgcn_mfma_f32_16x16x32_bf16(afr[ks], wfr[kt][ks], pa[kt], 0, 0, 0);
        #pragma unroll
        for (int kt = 0; kt < 4; ++kt) {
            float v0 = pa[kt][0] + biasv[kt];
            float v1 = pa[kt][1] + biasv[kt];
            float v2 = pa[kt][2] + biasv[kt];
            float v3 = pa[kt][3] + biasv[kt];
            if (kt < 2) {   // k rows of this head
                v0 = __expf(v0); v1 = __expf(v1);
                v2 = __expf(v2); v3 = __expf(v3);
                sacc[kt] += (v0 + v1) + (v2 + v3);
            }
            uint2 w;
            w.x = pack2(v0, v1);
            w.y = pack2(v2, v3);
            *(uint2*)&Psw[(kt * 16 + m) * PS_STRIDE + nt * 8 + quad * 2] = w;
        }
    }
    // phase B: ctx += Ek V^T — reads ONLY this wave's Ps region (no barrier)
    #pragma unroll
    for (int ks = 0; ks < 2; ++ks) {
        short8 ea[2], vb[2];
        #pragma unroll
        for (int dt = 0; dt < 2; ++dt)
            ea[dt] = *(const short8*)&Psw[(dt * 16 + m) * PS_STRIDE + ks * 16 + quad * 4];
        #pragma unroll
        for (int et = 0; et < 2; ++et)
            vb[et] = *(const short8*)&Psw[(32 + et * 16 + m) * PS_STRIDE + ks * 16 + quad * 4];
        #pragma unroll
        for (int dt = 0; dt < 2; ++dt)
            #pragma unroll
            for (int et = 0; et < 2; ++et)
                acc2[dt * 2 + et] = __builtin_amdgcn_mfma_f32_16x16x32_bf16(ea[dt], vb[et], acc2[dt * 2 + et], 0, 0, 0);
    }
}

// ---------------- K1: projections + exp + partial context + group reduce ----------------
__global__ __launch_bounds__(256, 2) void k1_ctx(
    const float* __restrict__ x, const float* __restrict__ w_qkv,
    const float* __restrict__ b_qkv, float* __restrict__ cpart,
    float* __restrict__ ctxP, int* __restrict__ cnt, int nb1)
{
    // Xs[2][64*XS_STRIDE] | Ps[256*PS_STRIDE]; W staging reuses the front.
    __shared__ uint32_t smem[2 * 64 * XS_STRIDE + 256 * PS_STRIDE];
    __shared__ int isLast;
    uint32_t* const Xs0 = smem;
    uint32_t* const Xs1 = smem + 64 * XS_STRIDE;
    uint32_t* const Ps  = smem + 2 * 64 * XS_STRIDE;

    const int t = threadIdx.x;
    const int lane = t & 63;
    const int wavu = __builtin_amdgcn_readfirstlane(t >> 6);
    const int m = lane & 15, quad = lane >> 4;
    const int c0 = wavu * 32;
    uint32_t* const Psw = &Ps[wavu * 64 * PS_STRIDE];

    // contiguous tile run for this block
    const int T0 = NTILES / nb1, R = NTILES % nb1;
    const int b = blockIdx.x;
    const int cnt_tiles = T0 + (b < R ? 1 : 0);
    const int s0 = (b < R) ? b * (T0 + 1) : R * (T0 + 1) + (b - R) * T0;

    const float* xw = x + (size_t)c0 * NPOS + lane;   // wave's channel slab base
    float pfA[32], pfB[32];

    // issue first tile's loads immediately (overlap with W staging)
    k1_load(xw + (size_t)s0 * 64, pfA);

    // ---- W fragments via LDS staging, coalesced global reads ----
    short8 wfr[4][4];
    float biasv[4];
    float* const Wst = (float*)smem + wavu * (32 * WST_STRIDE);
    #pragma unroll
    for (int pass = 0; pass < 2; ++pass) {
        const int rbase = (pass == 0 ? 128 : 256) + wavu * 32;
        const float* g = w_qkv + (size_t)rbase * 128;
        #pragma unroll
        for (int i = 0; i < 64; ++i) {
            const int idx = i * 64 + lane;               // 256B coalesced
            Wst[(idx >> 7) * WST_STRIDE + (idx & 127)] = g[idx];
        }
        __syncthreads();
        #pragma unroll
        for (int kt = 0; kt < 2; ++kt) {
            const int lr = kt * 16 + m;
            #pragma unroll
            for (int ks = 0; ks < 4; ++ks) {
                const float* p = &Wst[lr * WST_STRIDE + ks * 32 + quad * 8];
                float4 a = *(const float4*)p;
                float4 c = *(const float4*)(p + 4);
                short8 w;
                w[0] = (short)f2bf(a.x); w[1] = (short)f2bf(a.y);
                w[2] = (short)f2bf(a.z); w[3] = (short)f2bf(a.w);
                w[4] = (short)f2bf(c.x); w[5] = (short)f2bf(c.y);
                w[6] = (short)f2bf(c.z); w[7] = (short)f2bf(c.w);
                wfr[pass * 2 + kt][ks] = w;
            }
            biasv[pass * 2 + kt] = b_qkv[rbase + kt * 16 + m];
        }
        __syncthreads();
    }

    floatx4 acc2[4];
    #pragma unroll
    for (int i = 0; i < 4; ++i) acc2[i] = (floatx4){0.f, 0.f, 0.f, 0.f};
    float sacc[2] = {0.f, 0.f};

    // prologue: pfA holds tile s0; load s0+1; stage s0 into Xs0
    if (cnt_tiles > 1) k1_load(xw + (size_t)(s0 + 1) * 64, pfB);
    k1_store(Xs0, pfA, lane, c0);
    __syncthreads();

    for (int i = 0; i < cnt_tiles; i += 2) {
        // --- half 1: consume Xs0, prefetch i+2 -> pfA, stage pfB -> Xs1
        if (i + 2 < cnt_tiles) k1_load(xw + (size_t)(s0 + i + 2) * 64, pfA);
        k1_tile(Xs0, Psw, wfr, biasv, acc2, sacc, m, quad);
        if (i + 1 < cnt_tiles) k1_store(Xs1, pfB, lane, c0);
        __syncthreads();
        // --- half 2: consume Xs1, prefetch i+3 -> pfB, stage pfA -> Xs0
        if (i + 1 < cnt_tiles) {
            if (i + 3 < cnt_tiles) k1_load(xw + (size_t)(s0 + i + 3) * 64, pfB);
            k1_tile(Xs1, Psw, wfr, biasv, acc2, sacc, m, quad);
            if (i + 2 < cnt_tiles) k1_store(Xs0, pfA, lane, c0);
            __syncthreads();
        }
    }

    // streaming partials: [0..4095] ctx (h*1024 + d*32 + e), [4096..4223] S
    float* __restrict__ dst = cpart + (size_t)b * 4224;
    #pragma unroll
    for (int dt = 0; dt < 2; ++dt)
        #pragma unroll
        for (int et = 0; et < 2; ++et)
            #pragma unroll
            for (int r = 0; r < 4; ++r) {
                const int d = dt * 16 + quad * 4 + r, e = et * 16 + m;
                dst[wavu * 1024 + d * 32 + e] = acc2[dt * 2 + et][r];
            }
    #pragma unroll
    for (int kt = 0; kt < 2; ++kt) {
        float s = sacc[kt];
        s += __shfl_down(s, 32, 64);
        s += __shfl_down(s, 16, 64);
        if (lane < 16) dst[4096 + wavu * 32 + kt * 16 + lane] = s;
    }

    // ---- last-arriver group reduction: group g = 64 blocks -> ctxP[g] ----
    __syncthreads();            // all stores of this block issued
    __threadfence();            // flush to device scope
    if (t == 0) {
        const int g = b >> 6;
        const int gsz = min(nb1 - (g << 6), 64);
        const int old = __hip_atomic_fetch_add(&cnt[g], 1, __ATOMIC_ACQ_REL,
                                               __HIP_MEMORY_SCOPE_AGENT);
        isLast = (old == gsz - 1);
    }
    __syncthreads();
    if (isLast) {
        __threadfence();        // acquire: invalidate stale cached lines
        const int g = b >> 6;
        const int b0 = g << 6;
        const int gsz = min(nb1 - b0, 64);
        float* __restrict__ out = ctxP + (size_t)g * 4224;
        for (int j0 = 0; j0 < 4224; j0 += 256) {
            const int j = j0 + t;
            if (j < 4224) {
                float s = 0.f;
                for (int bb = 0; bb < gsz; ++bb)
                    s += cpart[(size_t)(b0 + bb) * 4224 + j];
                out[j] = s;
            }
        }
    }
}

// ---------------- K2bc: per-o A row -> bf16 Bm row + cvec ----------------
__global__ __launch_bounds__(256) void k2bc(
    const float* __restrict__ ctxP, const float* __restrict__ w_out,
    const float* __restrict__ w_qkv, const float* __restrict__ b_qkv,
    const float* __restrict__ b_out, uint32_t* __restrict__ Bmb, float* __restrict__ cvec)
{
    __shared__ float ctx33[128 * 33];
    __shared__ float Ss[128];
    __shared__ float Arow[128];
    __shared__ float row[128];
    __shared__ float red[128];
    const int o = blockIdx.x, t = threadIdx.x;
    for (int j = t; j < 4224; j += 256) {
        float s = 0.f;
        #pragma unroll
        for (int p = 0; p < 8; ++p) s += ctxP[p * 4224 + j];
        if (j < 4096) ctx33[(j >> 5) * 33 + (j & 31)] = s;
        else          Ss[j - 4096] = s;
    }
    __syncthreads();
    if (t < 128) {   // A[o][hd], hd = t
        const int h = t >> 5;
        float s = 0.f;
        #pragma unroll
        for (int e = 0; e < 32; ++e)
            s = fmaf(w_out[o * 128 + h * 32 + e], ctx33[t * 33 + e], s);
        Arow[t] = s / Ss[t];
    }
    __syncthreads();
    if (t < 128) {   // Bm[o][c], c = t
        float s = 0.f;
        #pragma unroll 16
        for (int hd = 0; hd < 128; ++hd)
            s = fmaf(Arow[hd], w_qkv[hd * 128 + t], s);
        row[t] = s;
        red[t] = Arow[t] * b_qkv[t];
    }
    __syncthreads();
    if (t < 64) Bmb[o * 64 + t] = pack2(row[2 * t], row[2 * t + 1]);
    if (t == 0) {
        float cs = b_out[o];
        #pragma unroll 8
        for (int i = 0; i < 128; ++i) cs += red[i];
        cvec[o] = cs;
    }
}

// ---------------- K3: y = Bm @ x + cvec ----------------
__global__ __launch_bounds__(256) void k3(
    const float* __restrict__ x, const uint32_t* __restrict__ Bmb,
    const float* __restrict__ cvec, float* __restrict__ y)
{
    __shared__ uint32_t Xs[64 * XS_STRIDE];
    const int t = threadIdx.x, lane = t & 63;
    const int wavu = __builtin_amdgcn_readfirstlane(t >> 6);
    const int m = lane & 15, quad = lane >> 4;
    const int n0 = blockIdx.x * 64;
    const int c0 = wavu * 32;

    // stage X^T first (get loads in flight)
    float pf[32];
    k1_load(x + (size_t)c0 * NPOS + n0 + lane, pf);

    // Bm fragments from packed bf16 rows: 8 x dwordx4
    short8 bfr[2][4];
    float cv[2];
    #pragma unroll
    for (int ot = 0; ot < 2; ++ot) {
        const int o = (wavu * 2 + ot) * 16 + m;
        cv[ot] = cvec[o];
        #pragma unroll
        for (int ks = 0; ks < 4; ++ks)
            bfr[ot][ks] = *(const short8*)&Bmb[o * 64 + ks * 16 + quad * 4];
    }
    k1_store(Xs, pf, lane, c0);
    __syncthreads();

    floatx4 acc[2][4];
    #pragma unroll
    for (int ot = 0; ot < 2; ++ot)
        #pragma unroll
        for (int nt = 0; nt < 4; ++nt) acc[ot][nt] = (floatx4){0.f, 0.f, 0.f, 0.f};
    #pragma unroll
    for (int nt = 0; nt < 4; ++nt) {
        short8 afr[4];
        #pragma unroll
        for (int ks = 0; ks < 4; ++ks)
            afr[ks] = *(const short8*)&Xs[(nt * 16 + m) * XS_STRIDE + ks * 16 + quad * 4];
        #pragma unroll
        for (int ks = 0; ks < 4; ++ks)
            #pragma unroll
            for (int ot = 0; ot < 2; ++ot)
                acc[ot][nt] = __builtin_amdgcn_mfma_f32_16x16x32_bf16(afr[ks], bfr[ot][ks], acc[ot][nt], 0, 0, 0);
    }
    #pragma unroll
    for (int ot = 0; ot < 2; ++ot) {
        const int o = (wavu * 2 + ot) * 16 + m;
        #pragma unroll
        for (int nt = 0; nt < 4; ++nt) {
            floatx4 v = acc[ot][nt];
            v.x += cv[ot]; v.y += cv[ot]; v.z += cv[ot]; v.w += cv[ot];
            *(floatx4*)(y + (size_t)o * NPOS + n0 + nt * 16 + quad * 4) = v;
        }
    }
}

extern "C" void kernel_launch(void* const* d_in, const int* in_sizes, int n_in,
                              void* d_out, int out_size, void* d_ws, size_t ws_size,
                              hipStream_t stream)
{
    const float* x     = (const float*)d_in[0];
    const float* w_qkv = (const float*)d_in[1];
    const float* b_qkv = (const float*)d_in[2];
    const float* w_out = (const float*)d_in[3];
    const float* b_out = (const float*)d_in[4];
    float* y = (float*)d_out;

    // ws: cpart[nb1][4224] | ctxP[8][4224] | Bmb[8192 u32] | cvec[128] | cnt[16]
    const size_t tailf = (size_t)(8 * 4224 + 8192 + 128 + 16);
    int nb1 = NB1;
    if (ws_size < (tailf + (size_t)nb1 * 4224) * 4) {
        long cap = ((long)(ws_size / 4) - (long)tailf) / 4224;
        nb1 = (int)cap;
        if (nb1 < 1) nb1 = 1;
        if (nb1 > NB1) nb1 = NB1;
    }
    char* wsb = (char*)d_ws;
    float* cpart   = (float*)wsb;
    float* ctxP    = cpart + (size_t)nb1 * 4224;
    uint32_t* Bmb  = (uint32_t*)(ctxP + 8 * 4224);
    float* cvec    = (float*)(Bmb + 8192);
    int* cnt       = (int*)(cvec + 128);

    // zero ctxP (unused replicas must read 0) + Bmb + cvec + counters: one memset
    hipMemsetAsync(ctxP, 0, (size_t)(8 * 4224 + 8192 + 128 + 16) * 4, stream);
    hipLaunchKernelGGL(k1_ctx, dim3(nb1), dim3(256), 0, stream, x, w_qkv, b_qkv, cpart, ctxP, cnt, nb1);
    hipLaunchKernelGGL(k2bc, dim3(128), dim3(256), 0, stream, ctxP, w_out, w_qkv, b_qkv, b_out, Bmb, cvec);
    hipLaunchKernelGGL(k3, dim3(NTILES), dim3(256), 0, stream, x, Bmb, cvec, y);
}

// Round 4
// 183.522 us; speedup vs baseline: 2.7403x; 2.7403x over previous
//
#include <hip/hip_runtime.h>
#include <hip/hip_bf16.h>
#include <stdint.h>

// LinearTimeSelfAttention MI355X, round 8:
//  - Composition of the two proven wins, nothing new:
//    * R1's 3-dispatch pipeline + fence-free memory-side atomicAdd tail
//      (2.16M fp32 atomics ~20us; R3 proved fence-based alternatives are
//      catastrophic: acquire=L2 inv, release=L2 wb -> k1 380us).
//    * R2's k1 internals: LDS-staged W build (coalesced 256B loads, kills
//      the scattered-load startup convoy, proven -22us) + contiguous tile
//      runs per block.
// Folding: y = Bm@x + cvec; Bm = A@W_q; A = (W_out ctx)/S;
// ctx = sum_n e^k v^T; S = sum_n e^k.

#define NPOS 147456      // 384*384
#define NTILES 2304      // NPOS / 64
#define NB1 512          // 2 blocks/CU exactly

typedef __attribute__((ext_vector_type(8))) short short8;
typedef __attribute__((ext_vector_type(4))) float floatx4;

__device__ __forceinline__ uint16_t f2bf(float f) {
    uint32_t u = __float_as_uint(f);
    return (uint16_t)((u + 0x7fffu + ((u >> 16) & 1u)) >> 16);   // RNE
}
__device__ __forceinline__ uint32_t pack2(float a, float b) {
#if __has_builtin(__builtin_amdgcn_cvt_pk_bf16_f32)
    auto r = __builtin_amdgcn_cvt_pk_bf16_f32(a, b);
    uint32_t u; __builtin_memcpy(&u, &r, sizeof(u));
    return u;
#else
    return (uint32_t)f2bf(a) | ((uint32_t)f2bf(b) << 16);
#endif
}

// strides in 32-bit LDS words
#define XS_STRIDE 68     // 136 bf16 per n-row (128 ch + 8 pad)
#define PS_STRIDE 36     // 72 bf16 per kvrow (64 n + 8 pad)
#define WST_STRIDE 132   // W staging: 128 f32 + 4 pad

// ---- k1 helpers ----
__device__ __forceinline__ void k1_load(const float* __restrict__ xb, float* pf) {
    #pragma unroll
    for (int i = 0; i < 32; ++i) pf[i] = xb[(size_t)i * NPOS];
}
__device__ __forceinline__ void k1_store(uint32_t* Xsbuf, const float* pf, int lane, int c0) {
    #pragma unroll
    for (int i = 0; i < 8; ++i) {
        uint2 w;
        w.x = pack2(pf[i * 4 + 0], pf[i * 4 + 1]);
        w.y = pack2(pf[i * 4 + 2], pf[i * 4 + 3]);
        *(uint2*)&Xsbuf[lane * XS_STRIDE + (c0 + i * 4) / 2] = w;
    }
}
__device__ __forceinline__ void k1_tile(
    const uint32_t* __restrict__ Xsbuf, uint32_t* __restrict__ Psw,
    const short8 (&wfr)[4][4], const float (&biasv)[4],
    floatx4 (&acc2)[4], float (&sacc)[2], int m, int quad)
{
    // phase A: P^T[n][local kvrow] = X^T W^T + b   (local rows: 0-31 k, 32-63 v)
    #pragma unroll
    for (int nt = 0; nt < 4; ++nt) {
        short8 afr[4];
        #pragma unroll
        for (int ks = 0; ks < 4; ++ks)
            afr[ks] = *(const short8*)&Xsbuf[(nt * 16 + m) * XS_STRIDE + ks * 16 + quad * 4];
        floatx4 pa[4];
        #pragma unroll
        for (int kt = 0; kt < 4; ++kt) pa[kt] = (floatx4){0.f, 0.f, 0.f, 0.f};
        #pragma unroll
        for (int ks = 0; ks < 4; ++ks)
            #pragma unroll
            for (int kt = 0; kt < 4; ++kt)
                pa[kt] = __builtin_amdgcn_mfma_f32_16x16x32_bf16(afr[ks], wfr[kt][ks], pa[kt], 0, 0, 0);
        #pragma unroll
        for (int kt = 0; kt < 4; ++kt) {
            float v0 = pa[kt][0] + biasv[kt];
            float v1 = pa[kt][1] + biasv[kt];
            float v2 = pa[kt][2] + biasv[kt];
            float v3 = pa[kt][3] + biasv[kt];
            if (kt < 2) {   // k rows of this head
                v0 = __expf(v0); v1 = __expf(v1);
                v2 = __expf(v2); v3 = __expf(v3);
                sacc[kt] += (v0 + v1) + (v2 + v3);
            }
            uint2 w;
            w.x = pack2(v0, v1);
            w.y = pack2(v2, v3);
            *(uint2*)&Psw[(kt * 16 + m) * PS_STRIDE + nt * 8 + quad * 2] = w;
        }
    }
    // phase B: ctx += Ek V^T — reads ONLY this wave's Ps region (no barrier)
    #pragma unroll
    for (int ks = 0; ks < 2; ++ks) {
        short8 ea[2], vb[2];
        #pragma unroll
        for (int dt = 0; dt < 2; ++dt)
            ea[dt] = *(const short8*)&Psw[(dt * 16 + m) * PS_STRIDE + ks * 16 + quad * 4];
        #pragma unroll
        for (int et = 0; et < 2; ++et)
            vb[et] = *(const short8*)&Psw[(32 + et * 16 + m) * PS_STRIDE + ks * 16 + quad * 4];
        #pragma unroll
        for (int dt = 0; dt < 2; ++dt)
            #pragma unroll
            for (int et = 0; et < 2; ++et)
                acc2[dt * 2 + et] = __builtin_amdgcn_mfma_f32_16x16x32_bf16(ea[dt], vb[et], acc2[dt * 2 + et], 0, 0, 0);
    }
}

// ---------------- K1: projections + exp + partial context (atomic reduce) ----------------
__global__ __launch_bounds__(256, 2) void k1_ctx(
    const float* __restrict__ x, const float* __restrict__ w_qkv,
    const float* __restrict__ b_qkv, float* __restrict__ ctxP, int nb1)
{
    // Xs[2][64*XS_STRIDE] | Ps[256*PS_STRIDE]; W staging reuses the front.
    __shared__ uint32_t smem[2 * 64 * XS_STRIDE + 256 * PS_STRIDE];
    uint32_t* const Xs0 = smem;
    uint32_t* const Xs1 = smem + 64 * XS_STRIDE;
    uint32_t* const Ps  = smem + 2 * 64 * XS_STRIDE;

    const int t = threadIdx.x;
    const int lane = t & 63;
    const int wavu = __builtin_amdgcn_readfirstlane(t >> 6);
    const int m = lane & 15, quad = lane >> 4;
    const int c0 = wavu * 32;
    uint32_t* const Psw = &Ps[wavu * 64 * PS_STRIDE];

    // contiguous tile run for this block
    const int T0 = NTILES / nb1, R = NTILES % nb1;
    const int b = blockIdx.x;
    const int cnt_tiles = T0 + (b < R ? 1 : 0);
    const int s0 = (b < R) ? b * (T0 + 1) : R * (T0 + 1) + (b - R) * T0;

    const float* xw = x + (size_t)c0 * NPOS + lane;   // wave's channel slab base
    float pfA[32], pfB[32];

    // issue first tile's loads immediately (overlap with W staging)
    k1_load(xw + (size_t)s0 * 64, pfA);

    // ---- W fragments via LDS staging, coalesced global reads ----
    // wave h: pass 0 = k-rows 128+h*32..+31 (wfr[0],wfr[1]),
    //         pass 1 = v-rows 256+h*32..+31 (wfr[2],wfr[3])
    short8 wfr[4][4];
    float biasv[4];
    float* const Wst = (float*)smem + wavu * (32 * WST_STRIDE);
    #pragma unroll
    for (int pass = 0; pass < 2; ++pass) {
        const int rbase = (pass == 0 ? 128 : 256) + wavu * 32;
        const float* g = w_qkv + (size_t)rbase * 128;
        #pragma unroll
        for (int i = 0; i < 64; ++i) {
            const int idx = i * 64 + lane;               // 256B coalesced
            Wst[(idx >> 7) * WST_STRIDE + (idx & 127)] = g[idx];
        }
        __syncthreads();
        #pragma unroll
        for (int kt = 0; kt < 2; ++kt) {
            const int lr = kt * 16 + m;
            #pragma unroll
            for (int ks = 0; ks < 4; ++ks) {
                const float* p = &Wst[lr * WST_STRIDE + ks * 32 + quad * 8];
                float4 a = *(const float4*)p;
                float4 c = *(const float4*)(p + 4);
                short8 w;
                w[0] = (short)f2bf(a.x); w[1] = (short)f2bf(a.y);
                w[2] = (short)f2bf(a.z); w[3] = (short)f2bf(a.w);
                w[4] = (short)f2bf(c.x); w[5] = (short)f2bf(c.y);
                w[6] = (short)f2bf(c.z); w[7] = (short)f2bf(c.w);
                wfr[pass * 2 + kt][ks] = w;
            }
            biasv[pass * 2 + kt] = b_qkv[rbase + kt * 16 + m];
        }
        __syncthreads();
    }

    floatx4 acc2[4];
    #pragma unroll
    for (int i = 0; i < 4; ++i) acc2[i] = (floatx4){0.f, 0.f, 0.f, 0.f};
    float sacc[2] = {0.f, 0.f};

    // prologue: pfA holds tile s0; load s0+1; stage s0 into Xs0
    if (cnt_tiles > 1) k1_load(xw + (size_t)(s0 + 1) * 64, pfB);
    k1_store(Xs0, pfA, lane, c0);
    __syncthreads();

    for (int i = 0; i < cnt_tiles; i += 2) {
        // --- half 1: consume Xs0, prefetch i+2 -> pfA, stage pfB -> Xs1
        if (i + 2 < cnt_tiles) k1_load(xw + (size_t)(s0 + i + 2) * 64, pfA);
        k1_tile(Xs0, Psw, wfr, biasv, acc2, sacc, m, quad);
        if (i + 1 < cnt_tiles) k1_store(Xs1, pfB, lane, c0);
        __syncthreads();
        // --- half 2: consume Xs1, prefetch i+3 -> pfB, stage pfA -> Xs0
        if (i + 1 < cnt_tiles) {
            if (i + 3 < cnt_tiles) k1_load(xw + (size_t)(s0 + i + 3) * 64, pfB);
            k1_tile(Xs1, Psw, wfr, biasv, acc2, sacc, m, quad);
            if (i + 2 < cnt_tiles) k1_store(Xs0, pfA, lane, c0);
            __syncthreads();
        }
    }

    // atomic partial reduce into replica (blockIdx & 7), fence-free:
    // [0..4095] ctx (h*1024 + d*32 + e), [4096..4223] S
    float* __restrict__ dst = ctxP + (size_t)(b & 7) * 4224;
    #pragma unroll
    for (int dt = 0; dt < 2; ++dt)
        #pragma unroll
        for (int et = 0; et < 2; ++et)
            #pragma unroll
            for (int r = 0; r < 4; ++r) {
                const int d = dt * 16 + quad * 4 + r, e = et * 16 + m;
                atomicAdd(&dst[wavu * 1024 + d * 32 + e], acc2[dt * 2 + et][r]);
            }
    #pragma unroll
    for (int kt = 0; kt < 2; ++kt) {
        float s = sacc[kt];
        s += __shfl_down(s, 32, 64);
        s += __shfl_down(s, 16, 64);
        if (lane < 16) atomicAdd(&dst[4096 + wavu * 32 + kt * 16 + lane], s);
    }
}

// ---------------- K2bc: per-o A row -> bf16 Bm row + cvec ----------------
__global__ __launch_bounds__(256) void k2bc(
    const float* __restrict__ ctxP, const float* __restrict__ w_out,
    const float* __restrict__ w_qkv, const float* __restrict__ b_qkv,
    const float* __restrict__ b_out, uint32_t* __restrict__ Bmb, float* __restrict__ cvec)
{
    __shared__ float ctx33[128 * 33];
    __shared__ float Ss[128];
    __shared__ float Arow[128];
    __shared__ float row[128];
    __shared__ float red[128];
    const int o = blockIdx.x, t = threadIdx.x;
    for (int j = t; j < 4224; j += 256) {
        float s = 0.f;
        #pragma unroll
        for (int p = 0; p < 8; ++p) s += ctxP[p * 4224 + j];
        if (j < 4096) ctx33[(j >> 5) * 33 + (j & 31)] = s;
        else          Ss[j - 4096] = s;
    }
    __syncthreads();
    if (t < 128) {   // A[o][hd], hd = t
        const int h = t >> 5;
        float s = 0.f;
        #pragma unroll
        for (int e = 0; e < 32; ++e)
            s = fmaf(w_out[o * 128 + h * 32 + e], ctx33[t * 33 + e], s);
        Arow[t] = s / Ss[t];
    }
    __syncthreads();
    if (t < 128) {   // Bm[o][c], c = t
        float s = 0.f;
        #pragma unroll 16
        for (int hd = 0; hd < 128; ++hd)
            s = fmaf(Arow[hd], w_qkv[hd * 128 + t], s);
        row[t] = s;
        red[t] = Arow[t] * b_qkv[t];
    }
    __syncthreads();
    if (t < 64) Bmb[o * 64 + t] = pack2(row[2 * t], row[2 * t + 1]);
    if (t == 0) {
        float cs = b_out[o];
        #pragma unroll 8
        for (int i = 0; i < 128; ++i) cs += red[i];
        cvec[o] = cs;
    }
}

// ---------------- K3: y = Bm @ x + cvec ----------------
__global__ __launch_bounds__(256) void k3(
    const float* __restrict__ x, const uint32_t* __restrict__ Bmb,
    const float* __restrict__ cvec, float* __restrict__ y)
{
    __shared__ uint32_t Xs[64 * XS_STRIDE];
    const int t = threadIdx.x, lane = t & 63;
    const int wavu = __builtin_amdgcn_readfirstlane(t >> 6);
    const int m = lane & 15, quad = lane >> 4;
    const int n0 = blockIdx.x * 64;
    const int c0 = wavu * 32;

    // stage X^T first (get loads in flight)
    float pf[32];
    k1_load(x + (size_t)c0 * NPOS + n0 + lane, pf);

    // Bm fragments from packed bf16 rows: 8 x dwordx4
    short8 bfr[2][4];
    float cv[2];
    #pragma unroll
    for (int ot = 0; ot < 2; ++ot) {
        const int o = (wavu * 2 + ot) * 16 + m;
        cv[ot] = cvec[o];
        #pragma unroll
        for (int ks = 0; ks < 4; ++ks)
            bfr[ot][ks] = *(const short8*)&Bmb[o * 64 + ks * 16 + quad * 4];
    }
    k1_store(Xs, pf, lane, c0);
    __syncthreads();

    floatx4 acc[2][4];
    #pragma unroll
    for (int ot = 0; ot < 2; ++ot)
        #pragma unroll
        for (int nt = 0; nt < 4; ++nt) acc[ot][nt] = (floatx4){0.f, 0.f, 0.f, 0.f};
    #pragma unroll
    for (int nt = 0; nt < 4; ++nt) {
        short8 afr[4];
        #pragma unroll
        for (int ks = 0; ks < 4; ++ks)
            afr[ks] = *(const short8*)&Xs[(nt * 16 + m) * XS_STRIDE + ks * 16 + quad * 4];
        #pragma unroll
        for (int ks = 0; ks < 4; ++ks)
            #pragma unroll
            for (int ot = 0; ot < 2; ++ot)
                acc[ot][nt] = __builtin_amdgcn_mfma_f32_16x16x32_bf16(afr[ks], bfr[ot][ks], acc[ot][nt], 0, 0, 0);
    }
    #pragma unroll
    for (int ot = 0; ot < 2; ++ot) {
        const int o = (wavu * 2 + ot) * 16 + m;
        #pragma unroll
        for (int nt = 0; nt < 4; ++nt) {
            floatx4 v = acc[ot][nt];
            v.x += cv[ot]; v.y += cv[ot]; v.z += cv[ot]; v.w += cv[ot];
            *(floatx4*)(y + (size_t)o * NPOS + n0 + nt * 16 + quad * 4) = v;
        }
    }
}

extern "C" void kernel_launch(void* const* d_in, const int* in_sizes, int n_in,
                              void* d_out, int out_size, void* d_ws, size_t ws_size,
                              hipStream_t stream)
{
    const float* x     = (const float*)d_in[0];
    const float* w_qkv = (const float*)d_in[1];
    const float* b_qkv = (const float*)d_in[2];
    const float* w_out = (const float*)d_in[3];
    const float* b_out = (const float*)d_in[4];
    float* y = (float*)d_out;

    // ws: ctxP[8][4224] | Bmb[8192 u32] | cvec[128]   (~168 KB total)
    char* wsb = (char*)d_ws;
    float* ctxP    = (float*)wsb;
    uint32_t* Bmb  = (uint32_t*)(wsb + (size_t)8 * 4224 * 4);
    float* cvec    = (float*)(wsb + (size_t)8 * 4224 * 4 + (size_t)8192 * 4);

    hipMemsetAsync(ctxP, 0, (size_t)8 * 4224 * sizeof(float), stream);
    hipLaunchKernelGGL(k1_ctx, dim3(NB1), dim3(256), 0, stream, x, w_qkv, b_qkv, ctxP, NB1);
    hipLaunchKernelGGL(k2bc, dim3(128), dim3(256), 0, stream, ctxP, w_out, w_qkv, b_qkv, b_out, Bmb, cvec);
    hipLaunchKernelGGL(k3, dim3(NTILES), dim3(256), 0, stream, x, Bmb, cvec, y);
}